// Round 5
// baseline (386.329 us; speedup 1.0000x reference)
//
#include <hip/hip_runtime.h>

#define N_TOT   500000
#define M_Q     1024
#define QB      16
#define NSPLIT  16
#define CAND_MAX 8192

#define ARGMIN_BLKS 1024            // 64 query-tiles x 16 N-splits
#define HIST_BLKS   32
#define USAGE_BLKS  64
#define CROWS       16              // rows per copy block
#define COPY_BLKS   (N_TOT / CROWS) // 31250
#define HIST_CHUNK  (N_TOT / HIST_BLKS)   // 15625

static const unsigned OUT_ROWS  = 259u * (unsigned)N_TOT;     // 129,500,000
static const unsigned OUT_USAGE = OUT_ROWS;
static const unsigned OUT_IDX   = OUT_ROWS + (unsigned)N_TOT; // 130,000,000

// ---- ws layout (bytes) ----
#define WS_PARTKEY 0                 // M*NSPLIT f32 = 65536
#define WS_PARTIDX 65536             // M*NSPLIT i32 = 65536
#define WS_HISTP   131072            // 32*1024 i32  = 131072 (plain stores, no zeroing)
#define WS_V       262144            // 1 i32
#define WS_CNT     262148            // 1 i32
#define WS_KEYS    262152            // CAND_MAX u32 = 32768

// =====================  argmin: partial argmin of 0.5*|s|^2 - p.s  =================
__global__ __launch_bounds__(256) void k_argmin(
    const float* __restrict__ pts, const float* __restrict__ mpts,
    float* __restrict__ partKey, int* __restrict__ partIdx)
{
    const int b = blockIdx.x;
    const int qb = b & 63;
    const int ns = b >> 6;
    const int qbase = qb * QB;
    const int chunk = N_TOT / NSPLIT;   // 31250
    const int n0 = ns * chunk;
    const int n1 = n0 + chunk;

    __shared__ float qs[QB * 3];
    __shared__ float wk[4][QB];
    __shared__ int   wi[4][QB];
    const int tid = threadIdx.x;
    if (tid < QB * 3) qs[tid] = pts[qbase * 3 + tid];
    __syncthreads();

    float qx[QB], qy[QB], qz[QB];
#pragma unroll
    for (int i = 0; i < QB; i++) { qx[i] = qs[3*i]; qy[i] = qs[3*i+1]; qz[i] = qs[3*i+2]; }

    float bk[QB]; int bi[QB];
#pragma unroll
    for (int i = 0; i < QB; i++) { bk[i] = INFINITY; bi[i] = 0x7fffffff; }

    for (int n = n0 + tid; n < n1; n += 256) {
        float x = mpts[3*n+0], y = mpts[3*n+1], z = mpts[3*n+2];
        float h = 0.5f * (x*x + y*y + z*z);
#pragma unroll
        for (int i = 0; i < QB; i++) {
            float key = h - x*qx[i] - y*qy[i] - z*qz[i];
            bool lt = key < bk[i];      // strict < + ascending n => first-min kept
            bk[i] = lt ? key : bk[i];
            bi[i] = lt ? n   : bi[i];
        }
    }

    const int lane = tid & 63;
    const int wv   = tid >> 6;
#pragma unroll
    for (int off = 32; off > 0; off >>= 1) {
#pragma unroll
        for (int i = 0; i < QB; i++) {
            float ok = __shfl_down(bk[i], off, 64);
            int   oi = __shfl_down(bi[i], off, 64);
            if (ok < bk[i] || (ok == bk[i] && oi < bi[i])) { bk[i] = ok; bi[i] = oi; }
        }
    }
    if (lane == 0) {
#pragma unroll
        for (int i = 0; i < QB; i++) { wk[wv][i] = bk[i]; wi[wv][i] = bi[i]; }
    }
    __syncthreads();
    if (tid < QB) {
        float k = wk[0][tid]; int ix = wi[0][tid];
#pragma unroll
        for (int w = 1; w < 4; w++) {
            float ok = wk[w][tid]; int oi = wi[w][tid];
            if (ok < k || (ok == k && oi < ix)) { k = ok; ix = oi; }
        }
        partKey[(qbase + tid) * NSPLIT + ns] = k;
        partIdx[(qbase + tid) * NSPLIT + ns] = ix;
    }
}

// =====================  hist: per-block partial histogram  ==========================
__global__ __launch_bounds__(256) void k_hist(
    const int* __restrict__ usage, int* __restrict__ histPart)
{
    __shared__ int lh[1024];
    const int hb = blockIdx.x;
    const int tid = threadIdx.x;
    const int r0 = hb * HIST_CHUNK;
    const int r1 = r0 + HIST_CHUNK;
#pragma unroll
    for (int i = 0; i < 4; i++) lh[tid + i * 256] = 0;
    __syncthreads();
    for (int n = r0 + tid; n < r1; n += 256) {
        unsigned v = (unsigned)usage[n];
        if (v > 1023u) v = 1023u;
        atomicAdd(&lh[v], 1);
    }
    __syncthreads();
#pragma unroll
    for (int i = 0; i < 4; i++) {
        int bin = tid + i * 256;
        histPart[hb * 1024 + bin] = lh[bin];
    }
}

// =====================  scanV: total hist, scan, cutoff V, zero cnt  ===============
__global__ __launch_bounds__(1024) void k_scanV(
    const int* __restrict__ histPart, int* __restrict__ Vout, int* __restrict__ cnt)
{
    __shared__ int scan[1024];
    const int t = threadIdx.x;
    int h = 0;
#pragma unroll
    for (int b = 0; b < HIST_BLKS; b++) h += histPart[b * 1024 + t];
    scan[t] = h; __syncthreads();
    for (int off = 1; off < 1024; off <<= 1) {
        int add = (t >= off) ? scan[t - off] : 0;
        __syncthreads();
        scan[t] += add;
        __syncthreads();
    }
    int cum  = scan[t] - h;    // count(usage < t)
    int cumN = scan[t];        // count(usage <= t)
    if (cum < M_Q && cumN >= M_Q) { *Vout = t; *cnt = 0; }
}

// =====================  collect candidates (usage <= V), unordered  ================
__global__ __launch_bounds__(256) void k_collect(
    const int* __restrict__ usage, const int* __restrict__ Vp,
    int* __restrict__ cnt, unsigned* __restrict__ keys)
{
    const int V = *Vp;
    const int stride = gridDim.x * 256;
    for (int n = blockIdx.x * 256 + threadIdx.x; n < N_TOT; n += stride) {
        int u = usage[n];
        if (u <= V) {
            int p = atomicAdd(cnt, 1);
            if (p < CAND_MAX) keys[p] = ((unsigned)u << 19) | (unsigned)n;
        }
    }
}

// =====================  usage region: int4 -> float4 convert-copy  =================
__global__ __launch_bounds__(256) void k_usage(
    const int* __restrict__ usage, float* __restrict__ out)
{
    const int4* u4 = (const int4*)usage;
    float4* o4 = (float4*)(out + OUT_USAGE);   // 129.5e6 % 4 == 0: aligned
    const int TOT4 = N_TOT / 4;                // 125000
    const int stride = gridDim.x * 256;
    for (int g = blockIdx.x * 256 + threadIdx.x; g < TOT4; g += stride) {
        int4 u = u4[g];
        o4[g] = make_float4((float)u.x, (float)u.y, (float)u.z, (float)u.w);
    }
}

// =====================  final: sort, rank, idx out, usage bump  ====================
__global__ __launch_bounds__(1024) void k_final(
    const float* __restrict__ pts,
    const float* __restrict__ partKey, const int* __restrict__ partIdx,
    const int* __restrict__ cntP, const unsigned* __restrict__ keysG,
    float* __restrict__ out)
{
    __shared__ unsigned keys[CAND_MAX];
    __shared__ int      mscan[1024];
    const int t = threadIdx.x;

    // 1) reduce NSPLIT partials (ascending-n chunk order: strict <)
    float bk = INFINITY; int bi = 0x7fffffff;
#pragma unroll
    for (int s = 0; s < NSPLIT; s++) {
        float k = partKey[t * NSPLIT + s];
        int   i = partIdx[t * NSPLIT + s];
        if (k < bk) { bk = k; bi = i; }
    }
    float px = pts[3*t], py = pts[3*t+1], pz = pts[3*t+2];
    float d2 = px*px + py*py + pz*pz + 2.0f * bk;
    const bool mask = d2 > 1e-6f;   // sqrt(max(d2,1e-12)) > 1e-3

    // 2) load candidates, pad to next pow2 (C >= M_Q by construction of V)
    int C = *cntP; if (C > CAND_MAX) C = CAND_MAX;
    int P2 = 1; while (P2 < C) P2 <<= 1;
    for (int p = t; p < P2; p += 1024) keys[p] = (p < C) ? keysG[p] : 0xFFFFFFFFu;
    __syncthreads();

    // 3) bitonic sort ascending -> (usage asc, index asc) == lax.top_k order
    for (int k = 2; k <= P2; k <<= 1) {
        for (int j = k >> 1; j > 0; j >>= 1) {
            for (int i = t; i < P2; i += 1024) {
                int ixj = i ^ j;
                if (ixj > i) {
                    unsigned a = keys[i], bb = keys[ixj];
                    bool up = ((i & k) == 0);
                    if ((a > bb) == up) { keys[i] = bb; keys[ixj] = a; }
                }
            }
            __syncthreads();
        }
    }

    // 4) rank = cumsum(mask)-1 ; final idx; outputs
    mscan[t] = mask ? 1 : 0; __syncthreads();
    for (int off = 1; off < 1024; off <<= 1) {
        int add = (t >= off) ? mscan[t - off] : 0;
        __syncthreads();
        mscan[t] += add;
        __syncthreads();
    }
    int rank = mscan[t] - 1;
    int idx = mask ? (int)(keys[rank] & 0x7FFFFu) : bi;
    out[(size_t)OUT_IDX + (size_t)t] = (float)idx;
    atomicAdd(out + OUT_USAGE + idx, 1.0f);   // after k_usage wrote base usage
}

// =====================  row copy: LDS-staged, all dwordx4, runs LAST  ==============
__global__ __launch_bounds__(256) void k_copy(
    const float* __restrict__ mpts, const float* __restrict__ mdesc,
    float* __restrict__ out)
{
    __shared__ float smem[CROWS * 259];   // 16576 B
    const int cb  = blockIdx.x;           // 0..31249
    const int tid = threadIdx.x;
    const int n0  = cb * CROWS;

    // stage mdesc rows as the output image [CROWS][259] (cols 3..258)
    const float4* src = (const float4*)(mdesc + (size_t)n0 * 256);
#pragma unroll
    for (int it = 0; it < 4; it++) {
        int g = tid + it * 256;           // 0..1023 float4s
        float4 v = src[g];
        int e = g * 4;
        int r = e >> 8;
        int c = e & 255;
        float* d = smem + r * 259 + 3 + c;
        d[0] = v.x; d[1] = v.y; d[2] = v.z; d[3] = v.w;
    }
    if (tid < CROWS * 3) {
        int r = tid / 3, c = tid - r * 3;
        smem[r * 259 + c] = mpts[(size_t)n0 * 3 + tid];
    }
    __syncthreads();

    // store contiguous block span: 1036 aligned float4s
    float4* dst4 = (float4*)(out + (size_t)cb * (CROWS * 259));
    const float4* s4 = (const float4*)smem;
#pragma unroll
    for (int it = 0; it < 5; it++) {
        int g = tid + it * 256;
        if (g < CROWS * 259 / 4) dst4[g] = s4[g];
    }
}

extern "C" void kernel_launch(void* const* d_in, const int* in_sizes, int n_in,
                              void* d_out, int out_size, void* d_ws, size_t ws_size,
                              hipStream_t stream)
{
    (void)in_sizes; (void)n_in; (void)out_size; (void)ws_size;
    const float* pts   = (const float*)d_in[0];
    const float* mpts  = (const float*)d_in[2];
    const float* mdesc = (const float*)d_in[3];
    const int*   usage = (const int*)d_in[4];
    float* out = (float*)d_out;

    char* ws = (char*)d_ws;
    float*    partKey  = (float*)(ws + WS_PARTKEY);
    int*      partIdx  = (int*)(ws + WS_PARTIDX);
    int*      histPart = (int*)(ws + WS_HISTP);
    int*      Vp       = (int*)(ws + WS_V);
    int*      cnt      = (int*)(ws + WS_CNT);
    unsigned* keys     = (unsigned*)(ws + WS_KEYS);

    k_argmin<<<ARGMIN_BLKS, 256, 0, stream>>>(pts, mpts, partKey, partIdx);
    k_hist<<<HIST_BLKS, 256, 0, stream>>>(usage, histPart);
    k_scanV<<<1, 1024, 0, stream>>>(histPart, Vp, cnt);
    k_collect<<<64, 256, 0, stream>>>(usage, Vp, cnt, keys);
    k_usage<<<USAGE_BLKS, 256, 0, stream>>>(usage, out);
    k_final<<<1, 1024, 0, stream>>>(pts, partKey, partIdx, cnt, keys, out);
    k_copy<<<COPY_BLKS, 256, 0, stream>>>(mpts, mdesc, out);
}